// Round 1
// baseline (2136.642 us; speedup 1.0000x reference)
//
#include <hip/hip_runtime.h>
#include <stdint.h>

#define F 128
#define NREP 8          // histogram/cursor replicas (atomic contention /8)
#define GRID 960        // 960 blocks: needs only 240 of 256 CUs at 4 blk/CU -> co-residency margin
#define BLK 256
#define NWAVES (GRID * (BLK / 64))   // 3840 waves
#define NPW 3                        // nodes per wave: ceil(10000/3840)=3 (N must be <= 11520)
#define NSUB 32                      // 2-level barrier fan-in (GRID % NSUB == 0)
#define TM 32
#define KC 32

typedef float f32x2 __attribute__((ext_vector_type(2)));
typedef float f32x4 __attribute__((ext_vector_type(4)));
typedef _Float16 h2 __attribute__((ext_vector_type(2)));

union H4 { f32x2 f2; _Float16 h[4]; };
union H8 { f32x4 f4; h2 p[4]; _Float16 h[8]; };
union HS { _Float16 h; unsigned short u; };
union HP { uint32_t u; h2 p; };
typedef uint32_t ERec;   // low16 = src node, high16 = fp16 norm

// ---- two-level sense-reversing grid barrier (agent scope => cross-XCD safe) ----
// bs[0]=generation, bs[1]=root count, bs[2..2+NSUB)=sub counts. All zeroed by memset per run.
__device__ __forceinline__ void gridbar(int* bs) {
    __syncthreads();                                   // all block stores retired to L2
    if (threadIdx.x == 0) {
        int sub = blockIdx.x & (NSUB - 1);
        int g = __hip_atomic_load(&bs[0], __ATOMIC_RELAXED, __HIP_MEMORY_SCOPE_AGENT);
        int v = __hip_atomic_fetch_add(&bs[2 + sub], 1, __ATOMIC_ACQ_REL, __HIP_MEMORY_SCOPE_AGENT);
        if (v == (GRID / NSUB) - 1) {                  // last in sub-group
            __hip_atomic_store(&bs[2 + sub], 0, __ATOMIC_RELAXED, __HIP_MEMORY_SCOPE_AGENT);
            int r = __hip_atomic_fetch_add(&bs[1], 1, __ATOMIC_ACQ_REL, __HIP_MEMORY_SCOPE_AGENT);
            if (r == NSUB - 1) {                       // last overall: reset root, bump gen
                __hip_atomic_store(&bs[1], 0, __ATOMIC_RELAXED, __HIP_MEMORY_SCOPE_AGENT);
                __hip_atomic_fetch_add(&bs[0], 1, __ATOMIC_ACQ_REL, __HIP_MEMORY_SCOPE_AGENT);
            } else {
                while (__hip_atomic_load(&bs[0], __ATOMIC_ACQUIRE, __HIP_MEMORY_SCOPE_AGENT) == g)
                    __builtin_amdgcn_s_sleep(2);
            }
        } else {
            while (__hip_atomic_load(&bs[0], __ATOMIC_ACQUIRE, __HIP_MEMORY_SCOPE_AGENT) == g)
                __builtin_amdgcn_s_sleep(2);
        }
    }
    __syncthreads();
}

extern "C" __global__ __launch_bounds__(BLK, 4) void mega_kernel(
        const float* __restrict__ x, const int* __restrict__ row, const int* __restrict__ col,
        const float* __restrict__ kv, const float* __restrict__ wt,
        const float* __restrict__ W, const float* __restrict__ bias,
        float* __restrict__ out,
        int* bar, int* hist, int* cursor, float* dinv, int* locS, int* ctot,
        int* startp, ERec* edges, _Float16* xh, _Float16* cura, _Float16* curb,
        float* hbuf, int N, int E, int L) {
    const int tid  = threadIdx.x;
    const int gtid = blockIdx.x * BLK + tid;
    const int GSZ  = GRID * BLK;
    const int lane = tid & 63;
    const int wid  = tid >> 6;
    const int q    = lane >> 4;      // quarter 0..3
    const int li   = lane & 15;      // lane-in-quarter

    // 32.9 KB shared, time-multiplexed: scan ints -> upd accumulator -> GEMM tiles
    __shared__ float smem[TM * F + KC * 129];
    int* iws = (int*)smem;

    // ================= P1: replicated in-degree histogram + x -> fp16 =================
    {
        int rep = blockIdx.x & (NREP - 1);
        int* h = hist + (size_t)rep * N;
        for (int e = gtid; e < E; e += GSZ)
            atomicAdd(&h[__builtin_nontemporal_load(&col[e])], 1);
        int total4 = (N * F) / 4;
        for (int i = gtid; i < total4; i += GSZ) {
            f32x4 v = __builtin_nontemporal_load(&((const f32x4*)x)[i]);
            H4 p;
            p.h[0] = (_Float16)v.x; p.h[1] = (_Float16)v.y;
            p.h[2] = (_Float16)v.z; p.h[3] = (_Float16)v.w;
            ((f32x2*)xh)[i] = p.f2;
        }
    }
    gridbar(bar);

    // ====== P2: degree = sum replicas, dinv = rsqrt, block-local scan (256/chunk) ======
    const int nchunk = (N + BLK - 1) / BLK;
    if (blockIdx.x < nchunk) {
        int n = blockIdx.x * BLK + tid;
        int d = 0;
        if (n < N) {
#pragma unroll
            for (int r = 0; r < NREP; ++r) d += hist[(size_t)r * N + n];
            int dc = d < 1 ? 1 : d;
            dinv[n] = rsqrtf((float)dc);
        }
        int inc = d;                                   // wave-inclusive scan
#pragma unroll
        for (int off = 1; off < 64; off <<= 1) {
            int t = __shfl_up(inc, off, 64);
            if (lane >= off) inc += t;
        }
        if (lane == 63) iws[wid] = inc;
        __syncthreads();
        if (wid == 0) {
            int wv_ = (lane < 4) ? iws[lane] : 0;
#pragma unroll
            for (int off = 1; off < 4; off <<= 1) {
                int t = __shfl_up(wv_, off, 64);
                if (lane >= off) wv_ += t;
            }
            if (lane < 4) iws[lane] = wv_;             // inclusive wave totals
        }
        __syncthreads();
        int woff = wid ? iws[wid - 1] : 0;
        if (n < N) locS[n] = woff + inc - d;           // exclusive within chunk
        if (tid == BLK - 1) ctot[blockIdx.x] = iws[3]; // chunk total
    }
    gridbar(bar);

    // ====== P3: every block redundantly prefixes chunk totals; seed cursors + startp ======
    {
        if (tid < 64) {
            int v = (tid < nchunk) ? ctot[tid] : 0;
#pragma unroll
            for (int off = 1; off < 64; off <<= 1) {
                int t = __shfl_up(v, off, 64);
                if (tid >= off) v += t;
            }
            iws[tid] = v;                              // inclusive chunk prefix
        }
        __syncthreads();
        for (int n = gtid; n < N; n += GSZ) {
            int ch = n >> 8;                           // BLK = 256 nodes per chunk
            int s0 = (ch ? iws[ch - 1] : 0) + locS[n];
            startp[n] = s0;
            int run = s0;
#pragma unroll
            for (int r = 0; r < NREP; ++r) {
                cursor[(size_t)r * N + n] = run;
                run += hist[(size_t)r * N + n];
            }
        }
        if (gtid == 0) startp[N] = iws[nchunk - 1];
    }
    gridbar(bar);

    // ================= P4: bucket scatter into packed 4B edge records =================
    {
        int rep = blockIdx.x & (NREP - 1);
        int* cur = cursor + (size_t)rep * N;
        for (int e = gtid; e < E; e += GSZ) {
            int c = __builtin_nontemporal_load(&col[e]);
            int r = __builtin_nontemporal_load(&row[e]);
            float nm = dinv[r] * dinv[c];
            int pos = atomicAdd(&cur[c], 1);
            HS hs_; hs_.h = (_Float16)nm;
            edges[pos] = (uint32_t)r | ((uint32_t)hs_.u << 16);
        }
    }
    gridbar(bar);

    // ============ persistent layer phase: wave owns NPW nodes across all layers ============
    const int wv = blockIdx.x * (BLK / 64) + wid;      // wave id 0..NWAVES-1
    float* updLds = smem;                              // per-(wave,node,li): 8 floats, stride 9

    if (q == 0) {                                      // zero update accumulators
#pragma unroll
        for (int s = 0; s < NPW; ++s) {
            float* u = updLds + ((wid * NPW + s) * 16 + li) * 9;
#pragma unroll
            for (int i = 0; i < 8; ++i) u[i] = 0.f;
        }
    }

    int ns_[NPW], ts_[NPW];
    ERec rec0[NPW];                                    // first-chunk records, reused 8 layers
    H8 own[NPW];                                       // own row in regs, reused 8 layers
#pragma unroll
    for (int s = 0; s < NPW; ++s) {
        int node = wv + s * NWAVES;
        int be = 0, en = 0;
        if (node < N) { be = startp[node]; en = startp[node + 1]; }
        ns_[s] = be; ts_[s] = en;
        int cnt0 = en - be; if (cnt0 > 64) cnt0 = 64;
        rec0[s] = (cnt0 > 0) ? edges[be + (lane < cnt0 ? lane : cnt0 - 1)] : 0u;
        f32x4 z = {0.f, 0.f, 0.f, 0.f};
        own[s].f4 = (node < N) ? ((const f32x4*)(xh + (size_t)node * F))[li] : z;
    }

    const _Float16* cin = xh;
    _Float16* cout = cura;
    for (int l = 0; l < L; ++l) {
        float tl = tanhf(kv[l]);
#pragma unroll
        for (int s = 0; s < NPW; ++s) {
            int node = wv + s * NWAVES;
            int valid = node < N;
            float a[8];
#pragma unroll
            for (int i = 0; i < 8; ++i) a[i] = 0.f;
            if (valid) {
                int be = ns_[s], en = ts_[s];
                for (int base = be; base < en; base += 64) {
                    int cnt = en - base; if (cnt > 64) cnt = 64;
                    ERec rec = (base == be) ? rec0[s]
                             : edges[base + (lane < cnt ? lane : cnt - 1)];
#pragma unroll
                    for (int ph = 0; ph < 2; ++ph) {
                        int j0 = ph * 32;
                        if (j0 < cnt) {                // wave-uniform predicate
                            uint32_t rr[8];
#pragma unroll
                            for (int u = 0; u < 8; ++u) {
                                int idx = j0 + 4 * u + q;
                                int ic  = idx < cnt ? idx : cnt - 1;
                                uint32_t r_ = (uint32_t)__shfl((int)rec, ic, 64);
                                if (idx >= cnt) r_ &= 0xffffu;   // zero norm -> fma adds 0
                                rr[u] = r_;
                            }
                            H8 vv[8];
#pragma unroll
                            for (int u = 0; u < 8; ++u)
                                vv[u].f4 = ((const f32x4*)(cin + (size_t)(rr[u] & 0xffffu) * F))[li];
                            h2 hacc[4];
#pragma unroll
                            for (int c = 0; c < 4; ++c) hacc[c] = (h2)(_Float16)0.f;
#pragma unroll
                            for (int u = 0; u < 8; ++u) {
                                HP nm; nm.u = (rr[u] >> 16) * 0x00010001u;
#pragma unroll
                                for (int c = 0; c < 4; ++c) hacc[c] += nm.p * vv[u].p[c];
                            }
#pragma unroll
                            for (int c = 0; c < 4; ++c) {
                                a[2 * c]     += (float)hacc[c][0];
                                a[2 * c + 1] += (float)hacc[c][1];
                            }
                        }
                    }
                }
#pragma unroll
                for (int i = 0; i < 8; ++i) {          // combine quarters
                    a[i] += __shfl_xor(a[i], 16, 64);
                    a[i] += __shfl_xor(a[i], 32, 64);
                }
                H8 o;
#pragma unroll
                for (int i = 0; i < 8; ++i)
                    o.h[i] = (_Float16)((float)own[s].h[i] - a[i]);
                own[s] = o;
                if (q == 0) {
                    float* u = updLds + ((wid * NPW + s) * 16 + li) * 9;
#pragma unroll
                    for (int i = 0; i < 8; ++i) u[i] += tl * (float)o.h[i];
                    if (l < L - 1)                     // last layer's cur is never gathered
                        ((f32x4*)(cout + (size_t)node * F))[li] = o.f4;
                }
            }
        }
        if (l < L - 1) gridbar(bar);                   // publish cur_l for next layer's gathers
        _Float16* nxt = (cin == xh) ? curb : (_Float16*)cin;
        cin = cout; cout = nxt;                        // ping-pong
    }

    // ============ h = sigmoid(wt)*update + (1-sigmoid(wt))*x  (fp32) ============
    {
        float cst  = 1.f / (1.f + __expf(-wt[0]));
        float cst1 = 1.f - cst;
#pragma unroll
        for (int s = 0; s < NPW; ++s) {
            int node = wv + s * NWAVES;
            if (node < N && q == 0) {
                const float* u = updLds + ((wid * NPW + s) * 16 + li) * 9;
                const f32x4* xr = (const f32x4*)(x + (size_t)node * F) + li * 2;
                f32x4 x0 = xr[0], x1 = xr[1];
                f32x4 h0, h1;
#pragma unroll
                for (int i = 0; i < 4; ++i) {
                    h0[i] = cst * u[i]     + cst1 * x0[i];
                    h1[i] = cst * u[4 + i] + cst1 * x1[i];
                }
                f32x4* hr = (f32x4*)(hbuf + (size_t)node * F) + li * 2;
                hr[0] = h0; hr[1] = h1;
            }
        }
    }
    gridbar(bar);

    // ================= GEMM epilogue: out = relu(h @ W^T + b) =================
    {
        float* hs = smem;                  // TM*F
        float* Wl = smem + TM * F;         // KC*129
        int ntile = (N + TM - 1) / TM;
        for (int tile = blockIdx.x; tile < ntile; tile += GRID) {
            int row0 = tile * TM;
            for (int j = tid; j < TM * 32; j += BLK) {
                int r = j >> 5, qd = j & 31;
                int gr = row0 + r;
                f32x4 hv = {0.f, 0.f, 0.f, 0.f};
                if (gr < N) hv = ((const f32x4*)(hbuf + (size_t)gr * F))[qd];
                ((f32x4*)hs)[j] = hv;
            }
            int c  = tid & 127;
            int rg = tid >> 7;
            float acc[16];
#pragma unroll
            for (int i = 0; i < 16; ++i) acc[i] = 0.f;
            for (int kc = 0; kc < F; kc += KC) {
                __syncthreads();
                for (int j = tid; j < KC * F; j += BLK) {
                    int c2 = j >> 5, kk = j & 31;
                    Wl[kk * 129 + c2] = W[(size_t)c2 * F + kc + kk];
                }
                __syncthreads();
#pragma unroll 8
                for (int kk = 0; kk < KC; ++kk) {
                    float w = Wl[kk * 129 + c];
#pragma unroll
                    for (int r = 0; r < 16; ++r)
                        acc[r] += hs[(rg * 16 + r) * F + kc + kk] * w;
                }
            }
            float bv = bias[c];
#pragma unroll
            for (int r = 0; r < 16; ++r) {
                int gr = row0 + rg * 16 + r;
                if (gr < N) {
                    float v = acc[r] + bv;
                    out[(size_t)gr * F + c] = v > 0.f ? v : 0.f;
                }
            }
            __syncthreads();
        }
    }
}

extern "C" void kernel_launch(void* const* d_in, const int* in_sizes, int n_in,
                              void* d_out, int out_size, void* d_ws, size_t ws_size,
                              hipStream_t stream) {
    const float* x   = (const float*)d_in[0];
    const int*   ei  = (const int*)d_in[1];
    const float* kv  = (const float*)d_in[2];
    const float* wt  = (const float*)d_in[3];
    const float* W   = (const float*)d_in[4];
    const float* b   = (const float*)d_in[5];
    float* out = (float*)d_out;

    const int E = in_sizes[1] / 2;
    const int N = in_sizes[0] / F;
    const int L = in_sizes[2];
    const int* row = ei;           // edge_index[0]
    const int* col = ei + E;       // edge_index[1]
    const size_t NF = (size_t)N * F;

    size_t off = 0;
    auto alloc = [&](size_t bytes) {
        void* p = (char*)d_ws + off;
        off += (bytes + 255) & ~(size_t)255;
        return p;
    };
    int*      bar    = (int*)alloc(256);                    // barrier state (memset each run)
    int*      hist   = (int*)alloc((size_t)NREP * N * 4);   // contiguous after bar for 1 memset
    int*      cursor = (int*)alloc((size_t)NREP * N * 4);
    float*    dinv   = (float*)alloc((size_t)N * 4);
    int*      locS   = (int*)alloc((size_t)N * 4);
    int*      ctot   = (int*)alloc(64 * 4);
    int*      startp = (int*)alloc((size_t)(N + 1) * 4);
    ERec*     edges  = (ERec*)alloc((size_t)E * sizeof(ERec));
    _Float16* xh     = (_Float16*)alloc(NF * 2);
    _Float16* cura   = (_Float16*)alloc(NF * 2);
    _Float16* curb   = (_Float16*)alloc(NF * 2);
    float*    hbuf   = (float*)alloc(NF * 4);
    (void)ws_size;

    (void)hipMemsetAsync(bar, 0, 256 + (size_t)NREP * N * 4, stream);

    mega_kernel<<<GRID, BLK, 0, stream>>>(x, row, col, kv, wt, W, b, out,
        bar, hist, cursor, dinv, locS, ctot, startp, edges, xh, cura, curb,
        hbuf, N, E, L);
}

// Round 2
// 541.494 us; speedup vs baseline: 3.9458x; 3.9458x over previous
//
#include <hip/hip_runtime.h>
#include <stdint.h>

#define F 128
#define NREP 8          // histogram/cursor replicas (atomic contention /8)
#define GRID 960        // 240 of 256 CUs at 4 blk/CU -> guaranteed co-residency margin
#define BLK 256
#define NWAVES (GRID * (BLK / 64))   // 3840 waves
#define NPW 3                        // nodes per wave: ceil(10000/3840)=3 (N must be <= 11520)
#define NSUB 32                      // 2-level barrier fan-in (GRID % NSUB == 0)
#define GPS (GRID / NSUB)            // blocks per sub-group
#define TM 32
#define KC 32

typedef float f32x2 __attribute__((ext_vector_type(2)));
typedef float f32x4 __attribute__((ext_vector_type(4)));
typedef _Float16 h2 __attribute__((ext_vector_type(2)));

union H4 { f32x2 f2; _Float16 h[4]; };
union H8 { f32x4 f4; h2 p[4]; _Float16 h[8]; };
union HS { _Float16 h; unsigned short u; };
union HP { uint32_t u; h2 p; };
typedef uint32_t ERec;   // low16 = src node, high16 = fp16 norm

// ---- grid barrier, epoch-based, monotonic counters (no resets -> no races) ----
// Layout (ints): bs[0]=generation (polled line); bs[32*(1+s)]=sub-counter s (own 128B line);
// bs[1056]=root counter (own line). All zeroed by one memset per run.
// Coherence: ONE release fence (wb L2) at arrival, relaxed LLC polling (NO per-poll
// invalidate -- the R1 bug), ONE acquire fence (inv L1+L2) at exit.
__device__ __forceinline__ void gridbar(int* bs, int g) {
    __syncthreads();                                   // block stores retired to L2 (vmcnt drain)
    if (threadIdx.x == 0) {
        __builtin_amdgcn_fence(__ATOMIC_RELEASE, "agent");   // wb dirty L2 -> LLC, once
        int sub = blockIdx.x & (NSUB - 1);
        int v = __hip_atomic_fetch_add(&bs[32 * (1 + sub)], 1,
                                       __ATOMIC_RELAXED, __HIP_MEMORY_SCOPE_AGENT);
        if (v == (g + 1) * GPS - 1) {                  // last arrival in sub-group, epoch g
            int r = __hip_atomic_fetch_add(&bs[1056], 1,
                                           __ATOMIC_RELAXED, __HIP_MEMORY_SCOPE_AGENT);
            if (r == (g + 1) * NSUB - 1)               // last sub-group overall
                __hip_atomic_store(&bs[0], g + 1,
                                   __ATOMIC_RELEASE, __HIP_MEMORY_SCOPE_AGENT);
        }
        while (__hip_atomic_load(&bs[0], __ATOMIC_RELAXED, __HIP_MEMORY_SCOPE_AGENT) <= g)
            __builtin_amdgcn_s_sleep(2);
        __builtin_amdgcn_fence(__ATOMIC_ACQUIRE, "agent");   // inv L1 + XCD L2, once
    }
    __syncthreads();
}

extern "C" __global__ __launch_bounds__(BLK, 4) void mega_kernel(
        const float* __restrict__ x, const int* __restrict__ row, const int* __restrict__ col,
        const float* __restrict__ kv, const float* __restrict__ wt,
        const float* __restrict__ W, const float* __restrict__ bias,
        float* __restrict__ out,
        int* bar, int* hist, int* cursor, float* dinv, int* locS, int* ctot,
        int* startp, ERec* edges, _Float16* xh, _Float16* cura, _Float16* curb,
        float* hbuf, int N, int E, int L) {
    const int tid  = threadIdx.x;
    const int gtid = blockIdx.x * BLK + tid;
    const int GSZ  = GRID * BLK;
    const int lane = tid & 63;
    const int wid  = tid >> 6;
    const int q    = lane >> 4;      // quarter 0..3
    const int li   = lane & 15;      // lane-in-quarter
    int bep = 0;                     // barrier epoch (identical sequence on all blocks)

    // 32.9 KB shared, time-multiplexed: scan ints -> upd accumulator -> GEMM tiles
    __shared__ float smem[TM * F + KC * 129];
    int* iws = (int*)smem;

    // ================= P1: replicated in-degree histogram + x -> fp16 =================
    {
        int rep = blockIdx.x & (NREP - 1);
        int* h = hist + (size_t)rep * N;
        for (int e = gtid; e < E; e += GSZ)
            atomicAdd(&h[__builtin_nontemporal_load(&col[e])], 1);
        int total4 = (N * F) / 4;
        for (int i = gtid; i < total4; i += GSZ) {
            f32x4 v = __builtin_nontemporal_load(&((const f32x4*)x)[i]);
            H4 p;
            p.h[0] = (_Float16)v.x; p.h[1] = (_Float16)v.y;
            p.h[2] = (_Float16)v.z; p.h[3] = (_Float16)v.w;
            ((f32x2*)xh)[i] = p.f2;
        }
    }
    gridbar(bar, bep++);

    // ====== P2: degree = sum replicas, dinv = rsqrt, block-local scan (256/chunk) ======
    const int nchunk = (N + BLK - 1) / BLK;
    if (blockIdx.x < nchunk) {
        int n = blockIdx.x * BLK + tid;
        int d = 0;
        if (n < N) {
#pragma unroll
            for (int r = 0; r < NREP; ++r) d += hist[(size_t)r * N + n];
            int dc = d < 1 ? 1 : d;
            dinv[n] = rsqrtf((float)dc);
        }
        int inc = d;                                   // wave-inclusive scan
#pragma unroll
        for (int off = 1; off < 64; off <<= 1) {
            int t = __shfl_up(inc, off, 64);
            if (lane >= off) inc += t;
        }
        if (lane == 63) iws[wid] = inc;
        __syncthreads();
        if (wid == 0) {
            int wv_ = (lane < 4) ? iws[lane] : 0;
#pragma unroll
            for (int off = 1; off < 4; off <<= 1) {
                int t = __shfl_up(wv_, off, 64);
                if (lane >= off) wv_ += t;
            }
            if (lane < 4) iws[lane] = wv_;             // inclusive wave totals
        }
        __syncthreads();
        int woff = wid ? iws[wid - 1] : 0;
        if (n < N) locS[n] = woff + inc - d;           // exclusive within chunk
        if (tid == BLK - 1) ctot[blockIdx.x] = iws[3]; // chunk total
    }
    gridbar(bar, bep++);

    // ====== P3: every block redundantly prefixes chunk totals; seed cursors + startp ======
    {
        if (tid < 64) {
            int v = (tid < nchunk) ? ctot[tid] : 0;
#pragma unroll
            for (int off = 1; off < 64; off <<= 1) {
                int t = __shfl_up(v, off, 64);
                if (tid >= off) v += t;
            }
            iws[tid] = v;                              // inclusive chunk prefix
        }
        __syncthreads();
        for (int n = gtid; n < N; n += GSZ) {
            int ch = n >> 8;                           // BLK = 256 nodes per chunk
            int s0 = (ch ? iws[ch - 1] : 0) + locS[n];
            startp[n] = s0;
            int run = s0;
#pragma unroll
            for (int r = 0; r < NREP; ++r) {
                cursor[(size_t)r * N + n] = run;
                run += hist[(size_t)r * N + n];
            }
        }
        if (gtid == 0) startp[N] = iws[nchunk - 1];
    }
    gridbar(bar, bep++);

    // ================= P4: bucket scatter into packed 4B edge records =================
    {
        int rep = blockIdx.x & (NREP - 1);
        int* cur = cursor + (size_t)rep * N;
        for (int e = gtid; e < E; e += GSZ) {
            int c = __builtin_nontemporal_load(&col[e]);
            int r = __builtin_nontemporal_load(&row[e]);
            float nm = dinv[r] * dinv[c];
            int pos = atomicAdd(&cur[c], 1);
            HS hs_; hs_.h = (_Float16)nm;
            edges[pos] = (uint32_t)r | ((uint32_t)hs_.u << 16);
        }
    }
    gridbar(bar, bep++);

    // ============ persistent layer phase: wave owns NPW nodes across all layers ============
    const int wv = blockIdx.x * (BLK / 64) + wid;      // wave id 0..NWAVES-1
    float* updLds = smem;                              // per-(wave,node,li): 8 floats, stride 9

    if (q == 0) {                                      // zero update accumulators
#pragma unroll
        for (int s = 0; s < NPW; ++s) {
            float* u = updLds + ((wid * NPW + s) * 16 + li) * 9;
#pragma unroll
            for (int i = 0; i < 8; ++i) u[i] = 0.f;
        }
    }

    int ns_[NPW], ts_[NPW];
    ERec rec0[NPW];                                    // first-chunk records, reused 8 layers
    H8 own[NPW];                                       // own row in regs, reused 8 layers
#pragma unroll
    for (int s = 0; s < NPW; ++s) {
        int node = wv + s * NWAVES;
        int be = 0, en = 0;
        if (node < N) { be = startp[node]; en = startp[node + 1]; }
        ns_[s] = be; ts_[s] = en;
        int cnt0 = en - be; if (cnt0 > 64) cnt0 = 64;
        rec0[s] = (cnt0 > 0) ? edges[be + (lane < cnt0 ? lane : cnt0 - 1)] : 0u;
        f32x4 z = {0.f, 0.f, 0.f, 0.f};
        own[s].f4 = (node < N) ? ((const f32x4*)(xh + (size_t)node * F))[li] : z;
    }

    const _Float16* cin = xh;
    _Float16* cout = cura;
    for (int l = 0; l < L; ++l) {
        float tl = tanhf(kv[l]);
#pragma unroll
        for (int s = 0; s < NPW; ++s) {
            int node = wv + s * NWAVES;
            int valid = node < N;
            float a[8];
#pragma unroll
            for (int i = 0; i < 8; ++i) a[i] = 0.f;
            if (valid) {
                int be = ns_[s], en = ts_[s];
                for (int base = be; base < en; base += 64) {
                    int cnt = en - base; if (cnt > 64) cnt = 64;
                    ERec rec = (base == be) ? rec0[s]
                             : edges[base + (lane < cnt ? lane : cnt - 1)];
#pragma unroll
                    for (int ph = 0; ph < 2; ++ph) {
                        int j0 = ph * 32;
                        if (j0 < cnt) {                // wave-uniform predicate
                            uint32_t rr[8];
#pragma unroll
                            for (int u = 0; u < 8; ++u) {
                                int idx = j0 + 4 * u + q;
                                int ic  = idx < cnt ? idx : cnt - 1;
                                uint32_t r_ = (uint32_t)__shfl((int)rec, ic, 64);
                                if (idx >= cnt) r_ &= 0xffffu;   // zero norm -> fma adds 0
                                rr[u] = r_;
                            }
                            H8 vv[8];
#pragma unroll
                            for (int u = 0; u < 8; ++u)
                                vv[u].f4 = ((const f32x4*)(cin + (size_t)(rr[u] & 0xffffu) * F))[li];
                            h2 hacc[4];
#pragma unroll
                            for (int c = 0; c < 4; ++c) hacc[c] = (h2)(_Float16)0.f;
#pragma unroll
                            for (int u = 0; u < 8; ++u) {
                                HP nm; nm.u = (rr[u] >> 16) * 0x00010001u;
#pragma unroll
                                for (int c = 0; c < 4; ++c) hacc[c] += nm.p * vv[u].p[c];
                            }
#pragma unroll
                            for (int c = 0; c < 4; ++c) {
                                a[2 * c]     += (float)hacc[c][0];
                                a[2 * c + 1] += (float)hacc[c][1];
                            }
                        }
                    }
                }
#pragma unroll
                for (int i = 0; i < 8; ++i) {          // combine quarters
                    a[i] += __shfl_xor(a[i], 16, 64);
                    a[i] += __shfl_xor(a[i], 32, 64);
                }
                H8 o;
#pragma unroll
                for (int i = 0; i < 8; ++i)
                    o.h[i] = (_Float16)((float)own[s].h[i] - a[i]);
                own[s] = o;
                if (q == 0) {
                    float* u = updLds + ((wid * NPW + s) * 16 + li) * 9;
#pragma unroll
                    for (int i = 0; i < 8; ++i) u[i] += tl * (float)o.h[i];
                    if (l < L - 1)                     // last layer's cur is never gathered
                        ((f32x4*)(cout + (size_t)node * F))[li] = o.f4;
                }
            }
        }
        if (l < L - 1) gridbar(bar, bep++);            // publish cur_l for next layer's gathers
        _Float16* nxt = (cin == xh) ? curb : (_Float16*)cin;
        cin = cout; cout = nxt;                        // ping-pong
    }

    // ============ h = sigmoid(wt)*update + (1-sigmoid(wt))*x  (fp32) ============
    {
        float cst  = 1.f / (1.f + __expf(-wt[0]));
        float cst1 = 1.f - cst;
#pragma unroll
        for (int s = 0; s < NPW; ++s) {
            int node = wv + s * NWAVES;
            if (node < N && q == 0) {
                const float* u = updLds + ((wid * NPW + s) * 16 + li) * 9;
                const f32x4* xr = (const f32x4*)(x + (size_t)node * F) + li * 2;
                f32x4 x0 = xr[0], x1 = xr[1];
                f32x4 h0, h1;
#pragma unroll
                for (int i = 0; i < 4; ++i) {
                    h0[i] = cst * u[i]     + cst1 * x0[i];
                    h1[i] = cst * u[4 + i] + cst1 * x1[i];
                }
                f32x4* hr = (f32x4*)(hbuf + (size_t)node * F) + li * 2;
                hr[0] = h0; hr[1] = h1;
            }
        }
    }
    gridbar(bar, bep++);

    // ================= GEMM epilogue: out = relu(h @ W^T + b) =================
    {
        float* hs = smem;                  // TM*F
        float* Wl = smem + TM * F;         // KC*129
        int ntile = (N + TM - 1) / TM;
        for (int tile = blockIdx.x; tile < ntile; tile += GRID) {
            int row0 = tile * TM;
            for (int j = tid; j < TM * 32; j += BLK) {
                int r = j >> 5, qd = j & 31;
                int gr = row0 + r;
                f32x4 hv = {0.f, 0.f, 0.f, 0.f};
                if (gr < N) hv = ((const f32x4*)(hbuf + (size_t)gr * F))[qd];
                ((f32x4*)hs)[j] = hv;
            }
            int c  = tid & 127;
            int rg = tid >> 7;
            float acc[16];
#pragma unroll
            for (int i = 0; i < 16; ++i) acc[i] = 0.f;
            for (int kc = 0; kc < F; kc += KC) {
                __syncthreads();
                for (int j = tid; j < KC * F; j += BLK) {
                    int c2 = j >> 5, kk = j & 31;
                    Wl[kk * 129 + c2] = W[(size_t)c2 * F + kc + kk];
                }
                __syncthreads();
#pragma unroll 8
                for (int kk = 0; kk < KC; ++kk) {
                    float w = Wl[kk * 129 + c];
#pragma unroll
                    for (int r = 0; r < 16; ++r)
                        acc[r] += hs[(rg * 16 + r) * F + kc + kk] * w;
                }
            }
            float bv = bias[c];
#pragma unroll
            for (int r = 0; r < 16; ++r) {
                int gr = row0 + rg * 16 + r;
                if (gr < N) {
                    float v = acc[r] + bv;
                    out[(size_t)gr * F + c] = v > 0.f ? v : 0.f;
                }
            }
            __syncthreads();
        }
    }
}

extern "C" void kernel_launch(void* const* d_in, const int* in_sizes, int n_in,
                              void* d_out, int out_size, void* d_ws, size_t ws_size,
                              hipStream_t stream) {
    const float* x   = (const float*)d_in[0];
    const int*   ei  = (const int*)d_in[1];
    const float* kv  = (const float*)d_in[2];
    const float* wt  = (const float*)d_in[3];
    const float* W   = (const float*)d_in[4];
    const float* b   = (const float*)d_in[5];
    float* out = (float*)d_out;

    const int E = in_sizes[1] / 2;
    const int N = in_sizes[0] / F;
    const int L = in_sizes[2];
    const int* row = ei;           // edge_index[0]
    const int* col = ei + E;       // edge_index[1]
    const size_t NF = (size_t)N * F;

    size_t off = 0;
    auto alloc = [&](size_t bytes) {
        void* p = (char*)d_ws + off;
        off += (bytes + 255) & ~(size_t)255;
        return p;
    };
    int*      bar    = (int*)alloc(8192);                   // barrier state (memset each run)
    int*      hist   = (int*)alloc((size_t)NREP * N * 4);   // contiguous after bar for 1 memset
    int*      cursor = (int*)alloc((size_t)NREP * N * 4);
    float*    dinv   = (float*)alloc((size_t)N * 4);
    int*      locS   = (int*)alloc((size_t)N * 4);
    int*      ctot   = (int*)alloc(64 * 4);
    int*      startp = (int*)alloc((size_t)(N + 1) * 4);
    ERec*     edges  = (ERec*)alloc((size_t)E * sizeof(ERec));
    _Float16* xh     = (_Float16*)alloc(NF * 2);
    _Float16* cura   = (_Float16*)alloc(NF * 2);
    _Float16* curb   = (_Float16*)alloc(NF * 2);
    float*    hbuf   = (float*)alloc(NF * 4);
    (void)ws_size;

    (void)hipMemsetAsync(bar, 0, 8192 + (size_t)NREP * N * 4, stream);

    mega_kernel<<<GRID, BLK, 0, stream>>>(x, row, col, kv, wt, W, b, out,
        bar, hist, cursor, dinv, locS, ctot, startp, edges, xh, cura, curb,
        hbuf, N, E, L);
}

// Round 3
// 273.961 us; speedup vs baseline: 7.7991x; 1.9765x over previous
//
#include <hip/hip_runtime.h>
#include <stdint.h>

#define F 128
#define NREP 8          // histogram/cursor replicas (atomic contention /8)
#define GRID_S 960      // setup grid: <=4 blk/CU needed, capacity 8 -> co-residency safe
#define BLK 256
#define NSUB 32         // 2-level barrier fan-in (GRID_S % NSUB == 0)
#define GPS (GRID_S / NSUB)
#define TM 32
#define KC 32

typedef float f32x2 __attribute__((ext_vector_type(2)));
typedef float f32x4 __attribute__((ext_vector_type(4)));
typedef _Float16 h2 __attribute__((ext_vector_type(2)));

union H4 { f32x2 f2; _Float16 h[4]; };
union H8 { f32x4 f4; h2 p[4]; _Float16 h[8]; };
union HS { _Float16 h; unsigned short u; };
union HP { uint32_t u; h2 p; };
typedef uint32_t ERec;   // low16 = src node, high16 = fp16 norm

// ---- grid barrier, epoch-based, monotonic counters (R2-proven protocol) ----
// bs[0]=generation (own line); bs[32*(1+s)]=sub-counter s (own 128B line);
// bs[1056]=root counter (own line). Zeroed by memset per run.
// ONE release fence at arrival (wb L2), relaxed polling (no per-poll inv),
// ONE acquire fence at exit (inv L1+L2).
__device__ __forceinline__ void gridbar(int* bs, int g) {
    __syncthreads();
    if (threadIdx.x == 0) {
        __builtin_amdgcn_fence(__ATOMIC_RELEASE, "agent");
        int sub = blockIdx.x & (NSUB - 1);
        int v = __hip_atomic_fetch_add(&bs[32 * (1 + sub)], 1,
                                       __ATOMIC_RELAXED, __HIP_MEMORY_SCOPE_AGENT);
        if (v == (g + 1) * GPS - 1) {
            int r = __hip_atomic_fetch_add(&bs[1056], 1,
                                           __ATOMIC_RELAXED, __HIP_MEMORY_SCOPE_AGENT);
            if (r == (g + 1) * NSUB - 1)
                __hip_atomic_store(&bs[0], g + 1,
                                   __ATOMIC_RELEASE, __HIP_MEMORY_SCOPE_AGENT);
        }
        while (__hip_atomic_load(&bs[0], __ATOMIC_RELAXED, __HIP_MEMORY_SCOPE_AGENT) <= g)
            __builtin_amdgcn_s_sleep(2);
        __builtin_amdgcn_fence(__ATOMIC_ACQUIRE, "agent");
    }
    __syncthreads();
}

// ---- ONE cooperative setup kernel: hist+convert | deg/dinv+chunk-scan |
//      chunk-prefix+seed | bucket. Replaces 5 dispatches + serial scan. ----
extern "C" __global__ __launch_bounds__(BLK, 4) void setup_kernel(
        const float* __restrict__ x, const int* __restrict__ row, const int* __restrict__ col,
        int* bar, int* hist, int* cursor, float* dinv, int* locS, int* ctot,
        int* startp, ERec* edges, _Float16* xh, int N, int E) {
    const int tid  = threadIdx.x;
    const int gtid = blockIdx.x * BLK + tid;
    const int GSZ  = GRID_S * BLK;
    const int lane = tid & 63;
    const int wid  = tid >> 6;
    __shared__ int iws[64];

    // P1: replicated in-degree histogram + x -> fp16
    {
        int rep = blockIdx.x & (NREP - 1);
        int* h = hist + (size_t)rep * N;
        for (int e = gtid; e < E; e += GSZ)
            atomicAdd(&h[__builtin_nontemporal_load(&col[e])], 1);
        int total4 = (N * F) / 4;
        for (int i = gtid; i < total4; i += GSZ) {
            f32x4 v = __builtin_nontemporal_load(&((const f32x4*)x)[i]);
            H4 p;
            p.h[0] = (_Float16)v.x; p.h[1] = (_Float16)v.y;
            p.h[2] = (_Float16)v.z; p.h[3] = (_Float16)v.w;
            ((f32x2*)xh)[i] = p.f2;
        }
    }
    gridbar(bar, 0);

    // P2: degree = sum replicas, dinv, block-local exclusive scan per 256-chunk
    const int nchunk = (N + BLK - 1) / BLK;
    if (blockIdx.x < nchunk) {
        int n = blockIdx.x * BLK + tid;
        int d = 0;
        if (n < N) {
#pragma unroll
            for (int r = 0; r < NREP; ++r) d += hist[(size_t)r * N + n];
            int dc = d < 1 ? 1 : d;
            dinv[n] = rsqrtf((float)dc);
        }
        int inc = d;
#pragma unroll
        for (int off = 1; off < 64; off <<= 1) {
            int t = __shfl_up(inc, off, 64);
            if (lane >= off) inc += t;
        }
        if (lane == 63) iws[wid] = inc;
        __syncthreads();
        if (wid == 0) {
            int wv_ = (lane < 4) ? iws[lane] : 0;
#pragma unroll
            for (int off = 1; off < 4; off <<= 1) {
                int t = __shfl_up(wv_, off, 64);
                if (lane >= off) wv_ += t;
            }
            if (lane < 4) iws[lane] = wv_;
        }
        __syncthreads();
        int woff = wid ? iws[wid - 1] : 0;
        if (n < N) locS[n] = woff + inc - d;
        if (tid == BLK - 1) ctot[blockIdx.x] = iws[3];
    }
    gridbar(bar, 1);

    // P3: every block redundantly prefixes chunk totals; seed cursors + startp
    {
        if (tid < 64) {
            int v = (tid < nchunk) ? ctot[tid] : 0;
#pragma unroll
            for (int off = 1; off < 64; off <<= 1) {
                int t = __shfl_up(v, off, 64);
                if (tid >= off) v += t;
            }
            iws[tid] = v;
        }
        __syncthreads();
        for (int n = gtid; n < N; n += GSZ) {
            int ch = n >> 8;
            int s0 = (ch ? iws[ch - 1] : 0) + locS[n];
            startp[n] = s0;
            int run = s0;
#pragma unroll
            for (int r = 0; r < NREP; ++r) {
                cursor[(size_t)r * N + n] = run;
                run += hist[(size_t)r * N + n];
            }
        }
        if (gtid == 0) startp[N] = iws[nchunk - 1];
    }
    gridbar(bar, 2);

    // P4: bucket scatter into packed 4B edge records
    {
        int rep = blockIdx.x & (NREP - 1);
        int* cur = cursor + (size_t)rep * N;
        for (int e = gtid; e < E; e += GSZ) {
            int c = __builtin_nontemporal_load(&col[e]);
            int r = __builtin_nontemporal_load(&row[e]);
            float nm = dinv[r] * dinv[c];
            int pos = atomicAdd(&cur[c], 1);
            HS hs_; hs_.h = (_Float16)nm;
            edges[pos] = (uint32_t)r | ((uint32_t)hs_.u << 16);
        }
    }
}

// ---- one layer: round-0 proven kernel, verbatim (max TLP: 1 node/wave, no LDS) ----
__global__ __launch_bounds__(256) void layer_kernel(
        const _Float16* __restrict__ cin, _Float16* __restrict__ cout,
        const int* __restrict__ start, const ERec* __restrict__ edges, int N) {
    int node = (blockIdx.x * blockDim.x + threadIdx.x) >> 6;
    int lane = threadIdx.x & 63;
    if (node >= N) return;
    int q  = lane >> 4;        // quarter 0..3
    int li = lane & 15;        // lane-in-quarter
    int s = start[node], t = start[node + 1];

    float a[8];
#pragma unroll
    for (int i = 0; i < 8; ++i) a[i] = 0.f;

    for (int base = s; base < t; base += 64) {
        int cnt = t - base; if (cnt > 64) cnt = 64;
        ERec rec = edges[base + (lane < cnt ? lane : cnt - 1)];   // coalesced staging
#pragma unroll
        for (int ph = 0; ph < 2; ++ph) {
            int j0 = ph * 32;
            if (j0 < cnt) {                    // wave-uniform predicate
                uint32_t rr[8];
#pragma unroll
                for (int u = 0; u < 8; ++u) {  // broadcast 8 records first
                    int idx = j0 + 4 * u + q;
                    int ic  = idx < cnt ? idx : cnt - 1;
                    uint32_t r_ = (uint32_t)__shfl((int)rec, ic, 64);
                    if (idx >= cnt) r_ &= 0xffffu;   // zero norm -> fma adds 0
                    rr[u] = r_;
                }
                H8 v[8];
#pragma unroll
                for (int u = 0; u < 8; ++u)    // 8 independent loads, no fma between
                    v[u].f4 = ((const f32x4*)(cin + (size_t)(rr[u] & 0xffffu) * F))[li];
                h2 hacc[4];
#pragma unroll
                for (int c = 0; c < 4; ++c) hacc[c] = (h2)(_Float16)0.f;
#pragma unroll
                for (int u = 0; u < 8; ++u) {
                    HP n; n.u = (rr[u] >> 16) * 0x00010001u;   // dup norm both halves
#pragma unroll
                    for (int c = 0; c < 4; ++c) hacc[c] += n.p * v[u].p[c];  // pk_fma
                }
#pragma unroll
                for (int c = 0; c < 4; ++c) {  // flush to fp32 every 8 edges
                    a[2 * c]     += (float)hacc[c][0];
                    a[2 * c + 1] += (float)hacc[c][1];
                }
            }
        }
    }
    // combine quarters (lanes li, li+16, li+32, li+48 hold same columns)
#pragma unroll
    for (int i = 0; i < 8; ++i) {
        a[i] += __shfl_xor(a[i], 16, 64);
        a[i] += __shfl_xor(a[i], 32, 64);
    }
    if (q == 0) {
        H8 c; c.f4 = ((const f32x4*)(cin + (size_t)node * F))[li];
        H8 o;
#pragma unroll
        for (int i = 0; i < 8; ++i) o.h[i] = (_Float16)((float)c.h[i] - a[i]);
        __builtin_nontemporal_store(o.f4, &((f32x4*)(cout + (size_t)node * F))[li]);
    }
}

// ---- epilogue: round-0 proven kernel, verbatim ----
__global__ __launch_bounds__(256) void final_kernel(
        const float* __restrict__ x, const _Float16* __restrict__ curh,
        const float* __restrict__ W, const float* __restrict__ bias,
        const float* __restrict__ kv, const float* __restrict__ wt,
        float* __restrict__ out, int N, int L) {
    __shared__ float hs[TM * F];
    __shared__ float Wl[KC * 129];
    int tid  = threadIdx.x;
    int row0 = blockIdx.x * TM;
    float cst  = 1.f / (1.f + __expf(-wt[0]));
    float cst1 = 1.f - cst;
    float t[16];
    for (int l = 0; l < L; ++l) t[l] = tanhf(kv[l]);
    const size_t NF = (size_t)N * F;

    for (int j = tid; j < TM * 32; j += 256) {
        int r = j >> 5, qd = j & 31;
        int gr = row0 + r;
        f32x4 hv = {0.f, 0.f, 0.f, 0.f};
        if (gr < N) {
            f32x4 xv = __builtin_nontemporal_load(&((const f32x4*)(x + (size_t)gr * F))[qd]);
            float sx = 0.f, sy = 0.f, sz = 0.f, sw = 0.f;
            for (int l = 0; l < L; ++l) {
                H4 u;
                u.f2 = __builtin_nontemporal_load(
                    &((const f32x2*)(curh + (size_t)l * NF + (size_t)gr * F))[qd]);
                sx += t[l] * (float)u.h[0]; sy += t[l] * (float)u.h[1];
                sz += t[l] * (float)u.h[2]; sw += t[l] * (float)u.h[3];
            }
            hv.x = cst * sx + cst1 * xv.x;
            hv.y = cst * sy + cst1 * xv.y;
            hv.z = cst * sz + cst1 * xv.z;
            hv.w = cst * sw + cst1 * xv.w;
        }
        ((f32x4*)hs)[j] = hv;
    }

    int c  = tid & 127;
    int rg = tid >> 7;
    float acc[16];
#pragma unroll
    for (int i = 0; i < 16; ++i) acc[i] = 0.f;
    for (int kc = 0; kc < F; kc += KC) {
        __syncthreads();
        for (int j = tid; j < KC * F; j += 256) {
            int c2 = j >> 5, kk = j & 31;
            Wl[kk * 129 + c2] = W[(size_t)c2 * F + kc + kk];
        }
        __syncthreads();
#pragma unroll 8
        for (int kk = 0; kk < KC; ++kk) {
            float w = Wl[kk * 129 + c];
#pragma unroll
            for (int r = 0; r < 16; ++r)
                acc[r] += hs[(rg * 16 + r) * F + kc + kk] * w;
        }
    }
    float bv = bias[c];
#pragma unroll
    for (int r = 0; r < 16; ++r) {
        int gr = row0 + rg * 16 + r;
        if (gr < N) {
            float v = acc[r] + bv;
            out[(size_t)gr * F + c] = v > 0.f ? v : 0.f;
        }
    }
}

extern "C" void kernel_launch(void* const* d_in, const int* in_sizes, int n_in,
                              void* d_out, int out_size, void* d_ws, size_t ws_size,
                              hipStream_t stream) {
    const float* x   = (const float*)d_in[0];
    const int*   ei  = (const int*)d_in[1];
    const float* kv  = (const float*)d_in[2];
    const float* wt  = (const float*)d_in[3];
    const float* W   = (const float*)d_in[4];
    const float* b   = (const float*)d_in[5];
    float* out = (float*)d_out;

    const int E = in_sizes[1] / 2;
    const int N = in_sizes[0] / F;
    const int L = in_sizes[2];
    const int* row = ei;           // edge_index[0]
    const int* col = ei + E;       // edge_index[1]
    const size_t NF = (size_t)N * F;

    size_t off = 0;
    auto alloc = [&](size_t bytes) {
        void* p = (char*)d_ws + off;
        off += (bytes + 255) & ~(size_t)255;
        return p;
    };
    int*      bar    = (int*)alloc(8192);                   // barrier state (memset each run)
    int*      hist   = (int*)alloc((size_t)NREP * N * 4);   // contiguous after bar: 1 memset
    int*      cursor = (int*)alloc((size_t)NREP * N * 4);
    float*    dinv   = (float*)alloc((size_t)N * 4);
    int*      locS   = (int*)alloc((size_t)N * 4);
    int*      ctot   = (int*)alloc(64 * 4);
    int*      startp = (int*)alloc((size_t)(N + 1) * 4);
    ERec*     edges  = (ERec*)alloc((size_t)E * sizeof(ERec));
    _Float16* xh     = (_Float16*)alloc(NF * 2);
    _Float16* curh   = (_Float16*)alloc((size_t)L * NF * 2);
    (void)ws_size;

    (void)hipMemsetAsync(bar, 0, 8192 + (size_t)NREP * N * 4, stream);

    setup_kernel<<<GRID_S, BLK, 0, stream>>>(x, row, col, bar, hist, cursor,
        dinv, locS, ctot, startp, edges, xh, N, E);

    for (int l = 0; l < L; ++l) {
        const _Float16* cin = (l == 0) ? xh : curh + (size_t)(l - 1) * NF;
        _Float16* cout = curh + (size_t)l * NF;
        layer_kernel<<<(N * 64 + 255) / 256, 256, 0, stream>>>(cin, cout, startp, edges, N);
    }

    final_kernel<<<(N + TM - 1) / TM, 256, 0, stream>>>(x, curh, W, b, kv, wt, out, N, L);
}

// Round 4
// 228.680 us; speedup vs baseline: 9.3434x; 1.1980x over previous
//
#include <hip/hip_runtime.h>
#include <stdint.h>

#define F 128
#define NREP 8          // cursor/histogram replicas (contention /8)
#define EPT 4           // edges per thread in histogram/bucket (r5-r7 proven)
#define TM 32
#define KC 32

typedef float f32x2 __attribute__((ext_vector_type(2)));
typedef float f32x4 __attribute__((ext_vector_type(4)));
typedef _Float16 h2 __attribute__((ext_vector_type(2)));

union H4 { f32x2 f2; _Float16 h[4]; };
union H8 { f32x4 f4; h2 p[4]; _Float16 h[8]; };
union HS { _Float16 h; unsigned short u; };
union HP { uint32_t u; h2 p; };
typedef uint32_t ERec;   // low16 = src node, high16 = fp16 norm

// ---- 1. fused: x(fp32)->xh(fp16) + replicated in-degree histogram ----
__global__ void convdeg_kernel(const float* __restrict__ x, _Float16* __restrict__ xh,
                               int total4, const int* __restrict__ col,
                               int* __restrict__ hist, int E, int N) {
    int rep = blockIdx.x & (NREP - 1);
    int i0 = (blockIdx.x * blockDim.x + threadIdx.x) * EPT;
    int* h = hist + (size_t)rep * N;
#pragma unroll
    for (int u = 0; u < EPT; ++u) {
        int e = i0 + u;
        if (e < E) atomicAdd(&h[__builtin_nontemporal_load(&col[e])], 1);
    }
#pragma unroll
    for (int u = 0; u < EPT; ++u) {
        int i = i0 + u;
        if (i < total4) {
            f32x4 v = __builtin_nontemporal_load(&((const f32x4*)x)[i]);
            H4 p;
            p.h[0] = (_Float16)v.x; p.h[1] = (_Float16)v.y;
            p.h[2] = (_Float16)v.z; p.h[3] = (_Float16)v.w;
            ((f32x2*)xh)[i] = p.f2;            // reused by layer 0 -> keep cacheable
        }
    }
}

// ---- 2. FUSED single-block: deg-sum + dinv + exclusive scan + cursor seed ----
// (was 3 dispatches: sumdinv / scan / seed -- hist values now stay in registers)
__global__ __launch_bounds__(1024) void degscanseed_kernel(
        const int* __restrict__ hist, int* __restrict__ cursor,
        float* __restrict__ dinv, int* __restrict__ startp, int N) {
    __shared__ int wsum[16];
    __shared__ int carry_s;
    int tid = threadIdx.x, lane = tid & 63, wid = tid >> 6;
    if (tid == 0) carry_s = 0;
    __syncthreads();
    for (int base = 0; base < N; base += 1024) {
        int i = base + tid;
        int h[NREP];
        int d = 0;
        if (i < N) {
#pragma unroll
            for (int r = 0; r < NREP; ++r) {
                h[r] = hist[(size_t)r * N + i];
                d += h[r];
            }
            int dc = d < 1 ? 1 : d;
            dinv[i] = rsqrtf((float)dc);
        } else {
#pragma unroll
            for (int r = 0; r < NREP; ++r) h[r] = 0;
        }
        int inc = d;                              // wave-inclusive scan
        for (int off = 1; off < 64; off <<= 1) {
            int t = __shfl_up(inc, off, 64);
            if (lane >= off) inc += t;
        }
        if (lane == 63) wsum[wid] = inc;
        __syncthreads();
        if (wid == 0) {
            int wv = (lane < 16) ? wsum[lane] : 0;
            for (int off = 1; off < 16; off <<= 1) {
                int t = __shfl_up(wv, off, 64);
                if (lane >= off) wv += t;
            }
            if (lane < 16) wsum[lane] = wv;       // inclusive wave totals
        }
        __syncthreads();
        int carry = carry_s;
        int woff = (wid > 0) ? wsum[wid - 1] : 0;
        int st = carry + woff + inc - d;          // exclusive start
        if (i < N) {
            startp[i] = st;
            int run = st;
#pragma unroll
            for (int r = 0; r < NREP; ++r) {      // seed replicated cursors from regs
                cursor[(size_t)r * N + i] = run;
                run += h[r];
            }
        }
        __syncthreads();
        if (tid == 0) carry_s = carry + wsum[15];
        __syncthreads();
    }
    if (tid == 0) startp[N] = carry_s;
}

// ---- 3. bucket scatter: packed 4B records, pre-seeded replicated cursors ----
__global__ void bucket_kernel(const int* __restrict__ row, const int* __restrict__ col,
                              const float* __restrict__ dinv,
                              int* __restrict__ cursor, ERec* __restrict__ edges,
                              int E, int N) {
    int rep = blockIdx.x & (NREP - 1);
    int e0 = (blockIdx.x * blockDim.x + threadIdx.x) * EPT;
    int* cur = cursor + (size_t)rep * N;
    int cs[EPT], rs[EPT], pos[EPT];
    float nm[EPT];
#pragma unroll
    for (int u = 0; u < EPT; ++u) {
        int e = e0 + u;
        if (e < E) {
            cs[u] = __builtin_nontemporal_load(&col[e]);
            rs[u] = __builtin_nontemporal_load(&row[e]);
        }
    }
#pragma unroll
    for (int u = 0; u < EPT; ++u) {
        int e = e0 + u;
        if (e < E) {
            nm[u]  = dinv[rs[u]] * dinv[cs[u]];
            pos[u] = atomicAdd(&cur[cs[u]], 1);
        }
    }
#pragma unroll
    for (int u = 0; u < EPT; ++u) {
        int e = e0 + u;
        if (e < E) {
            HS hs; hs.h = (_Float16)nm[u];
            ERec rec = (uint32_t)rs[u] | ((uint32_t)hs.u << 16);
            edges[pos[u]] = rec;               // reused 8x by layers -> cacheable
        }
    }
}

// ---- 4. one layer: predicated two-phase pipelined gather ----
// CHANGE vs r15: cout store is now a REGULAR store (was nontemporal).
// cur_l (2.56 MB) fits in one XCD L2; nt was evicting it so next layer's
// random gathers paid HBM latency/BW (~13 us/layer -- the dominant cost).
__global__ __launch_bounds__(256) void layer_kernel(
        const _Float16* __restrict__ cin, _Float16* __restrict__ cout,
        const int* __restrict__ start, const ERec* __restrict__ edges, int N) {
    int node = (blockIdx.x * blockDim.x + threadIdx.x) >> 6;
    int lane = threadIdx.x & 63;
    if (node >= N) return;
    int q  = lane >> 4;        // quarter 0..3
    int li = lane & 15;        // lane-in-quarter
    int s = start[node], t = start[node + 1];

    float a[8];
#pragma unroll
    for (int i = 0; i < 8; ++i) a[i] = 0.f;

    for (int base = s; base < t; base += 64) {
        int cnt = t - base; if (cnt > 64) cnt = 64;
        ERec rec = edges[base + (lane < cnt ? lane : cnt - 1)];   // coalesced staging
#pragma unroll
        for (int ph = 0; ph < 2; ++ph) {
            int j0 = ph * 32;
            if (j0 < cnt) {                    // wave-uniform predicate
                uint32_t rr[8];
#pragma unroll
                for (int u = 0; u < 8; ++u) {  // broadcast 8 records first
                    int idx = j0 + 4 * u + q;
                    int ic  = idx < cnt ? idx : cnt - 1;
                    uint32_t r_ = (uint32_t)__shfl((int)rec, ic, 64);
                    if (idx >= cnt) r_ &= 0xffffu;   // zero norm -> fma adds 0
                    rr[u] = r_;
                }
                H8 v[8];
#pragma unroll
                for (int u = 0; u < 8; ++u)    // 8 independent loads, no fma between
                    v[u].f4 = ((const f32x4*)(cin + (size_t)(rr[u] & 0xffffu) * F))[li];
                h2 hacc[4];
#pragma unroll
                for (int c = 0; c < 4; ++c) hacc[c] = (h2)(_Float16)0.f;
#pragma unroll
                for (int u = 0; u < 8; ++u) {
                    HP n; n.u = (rr[u] >> 16) * 0x00010001u;   // dup norm both halves
#pragma unroll
                    for (int c = 0; c < 4; ++c) hacc[c] += n.p * v[u].p[c];  // pk_fma
                }
#pragma unroll
                for (int c = 0; c < 4; ++c) {  // flush to fp32 every 8 edges
                    a[2 * c]     += (float)hacc[c][0];
                    a[2 * c + 1] += (float)hacc[c][1];
                }
            }
        }
    }
    // combine quarters (lanes li, li+16, li+32, li+48 hold same columns)
#pragma unroll
    for (int i = 0; i < 8; ++i) {
        a[i] += __shfl_xor(a[i], 16, 64);
        a[i] += __shfl_xor(a[i], 32, 64);
    }
    if (q == 0) {
        H8 c; c.f4 = ((const f32x4*)(cin + (size_t)node * F))[li];
        H8 o;
#pragma unroll
        for (int i = 0; i < 8; ++i) o.h[i] = (_Float16)((float)c.h[i] - a[i]);
        ((f32x4*)(cout + (size_t)node * F))[li] = o.f4;   // cacheable: next layer gathers it
    }
}

// ---- 5. epilogue: update = sum_l tanh(k_l)*cur_l; h = c*upd+(1-c)*x;
//          out = relu(h @ W^T + b) ----
__global__ __launch_bounds__(256) void final_kernel(
        const float* __restrict__ x, const _Float16* __restrict__ curh,
        const float* __restrict__ W, const float* __restrict__ bias,
        const float* __restrict__ kv, const float* __restrict__ wt,
        float* __restrict__ out, int N, int L) {
    __shared__ float hs[TM * F];
    __shared__ float Wl[KC * 129];
    int tid  = threadIdx.x;
    int row0 = blockIdx.x * TM;
    float cst  = 1.f / (1.f + __expf(-wt[0]));
    float cst1 = 1.f - cst;
    float t[16];
    for (int l = 0; l < L; ++l) t[l] = tanhf(kv[l]);
    const size_t NF = (size_t)N * F;

    for (int j = tid; j < TM * 32; j += 256) {
        int r = j >> 5, qd = j & 31;
        int gr = row0 + r;
        f32x4 hv = {0.f, 0.f, 0.f, 0.f};
        if (gr < N) {
            f32x4 xv = __builtin_nontemporal_load(&((const f32x4*)(x + (size_t)gr * F))[qd]);
            float sx = 0.f, sy = 0.f, sz = 0.f, sw = 0.f;
            for (int l = 0; l < L; ++l) {
                H4 u;
                u.f2 = __builtin_nontemporal_load(
                    &((const f32x2*)(curh + (size_t)l * NF + (size_t)gr * F))[qd]);
                sx += t[l] * (float)u.h[0]; sy += t[l] * (float)u.h[1];
                sz += t[l] * (float)u.h[2]; sw += t[l] * (float)u.h[3];
            }
            hv.x = cst * sx + cst1 * xv.x;
            hv.y = cst * sy + cst1 * xv.y;
            hv.z = cst * sz + cst1 * xv.z;
            hv.w = cst * sw + cst1 * xv.w;
        }
        ((f32x4*)hs)[j] = hv;
    }

    int c  = tid & 127;
    int rg = tid >> 7;
    float acc[16];
#pragma unroll
    for (int i = 0; i < 16; ++i) acc[i] = 0.f;
    for (int kc = 0; kc < F; kc += KC) {
        __syncthreads();
        for (int j = tid; j < KC * F; j += 256) {
            int c2 = j >> 5, kk = j & 31;
            Wl[kk * 129 + c2] = W[(size_t)c2 * F + kc + kk];
        }
        __syncthreads();
#pragma unroll 8
        for (int kk = 0; kk < KC; ++kk) {
            float w = Wl[kk * 129 + c];
#pragma unroll
            for (int r = 0; r < 16; ++r)
                acc[r] += hs[(rg * 16 + r) * F + kc + kk] * w;
        }
    }
    float bv = bias[c];
#pragma unroll
    for (int r = 0; r < 16; ++r) {
        int gr = row0 + rg * 16 + r;
        if (gr < N) {
            float v = acc[r] + bv;
            out[(size_t)gr * F + c] = v > 0.f ? v : 0.f;
        }
    }
}

extern "C" void kernel_launch(void* const* d_in, const int* in_sizes, int n_in,
                              void* d_out, int out_size, void* d_ws, size_t ws_size,
                              hipStream_t stream) {
    const float* x   = (const float*)d_in[0];
    const int*   ei  = (const int*)d_in[1];
    const float* kv  = (const float*)d_in[2];
    const float* wt  = (const float*)d_in[3];
    const float* W   = (const float*)d_in[4];
    const float* b   = (const float*)d_in[5];
    float* out = (float*)d_out;

    const int E = in_sizes[1] / 2;
    const int N = in_sizes[0] / F;
    const int L = in_sizes[2];
    const int* row = ei;           // edge_index[0]
    const int* col = ei + E;       // edge_index[1]
    const size_t NF = (size_t)N * F;
    const int total4 = (int)(NF / 4);

    size_t off = 0;
    auto alloc = [&](size_t bytes) {
        void* p = (char*)d_ws + off;
        off += (bytes + 255) & ~(size_t)255;
        return p;
    };
    int*      hist   = (int*)alloc((size_t)NREP * N * 4);
    int*      cursor = (int*)alloc((size_t)NREP * N * 4);
    int*      startp = (int*)alloc((size_t)(N + 1) * 4);
    float*    dinv   = (float*)alloc((size_t)N * 4);
    ERec*     edges  = (ERec*)alloc((size_t)E * sizeof(ERec));
    _Float16* xh     = (_Float16*)alloc(NF * 2);
    _Float16* curh   = (_Float16*)alloc((size_t)L * NF * 2);
    (void)ws_size;

    (void)hipMemsetAsync(hist, 0, (size_t)NREP * N * 4, stream);

    const int work = (E > total4 ? E : total4);
    const int nb_edge = (work + 256 * EPT - 1) / (256 * EPT);   // same geometry for bucket
    convdeg_kernel<<<nb_edge, 256, 0, stream>>>(x, xh, total4, col, hist, E, N);
    degscanseed_kernel<<<1, 1024, 0, stream>>>(hist, cursor, dinv, startp, N);
    bucket_kernel<<<nb_edge, 256, 0, stream>>>(row, col, dinv, cursor, edges, E, N);

    for (int l = 0; l < L; ++l) {
        const _Float16* cin = (l == 0) ? xh : curh + (size_t)(l - 1) * NF;
        _Float16* cout = curh + (size_t)l * NF;
        layer_kernel<<<(N * 64 + 255) / 256, 256, 0, stream>>>(cin, cout, startp, edges, N);
    }

    final_kernel<<<(N + TM - 1) / TM, 256, 0, stream>>>(x, curh, W, b, kv, wt, out, N, L);
}

// Round 5
// 214.622 us; speedup vs baseline: 9.9554x; 1.0655x over previous
//
#include <hip/hip_runtime.h>
#include <stdint.h>

#define F 128
#define NREP 8          // cursor/histogram replicas (contention /8)
#define EPT 4           // edges per thread in histogram/bucket (r5-r7 proven)
#define TM 32
#define KC 32

// decoupled-lookback flag/value packing: E=320000 < 2^25, flags in bits 29/30
#define AGGF  (1u << 29)
#define PREFF (1u << 30)
#define VMASK ((1u << 25) - 1)

typedef float f32x2 __attribute__((ext_vector_type(2)));
typedef float f32x4 __attribute__((ext_vector_type(4)));
typedef _Float16 h2 __attribute__((ext_vector_type(2)));

union H4 { f32x2 f2; _Float16 h[4]; };
union H8 { f32x4 f4; h2 p[4]; _Float16 h[8]; };
union HS { _Float16 h; unsigned short u; };
union HP { uint32_t u; h2 p; };
typedef uint32_t ERec;   // low16 = src node, high16 = fp16 norm

// ---- 1. fused: x(fp32)->xh(fp16) + replicated in-degree histogram ----
__global__ void convdeg_kernel(const float* __restrict__ x, _Float16* __restrict__ xh,
                               int total4, const int* __restrict__ col,
                               int* __restrict__ hist, int E, int N) {
    int rep = blockIdx.x & (NREP - 1);
    int i0 = (blockIdx.x * blockDim.x + threadIdx.x) * EPT;
    int* h = hist + (size_t)rep * N;
#pragma unroll
    for (int u = 0; u < EPT; ++u) {
        int e = i0 + u;
        if (e < E) atomicAdd(&h[__builtin_nontemporal_load(&col[e])], 1);
    }
#pragma unroll
    for (int u = 0; u < EPT; ++u) {
        int i = i0 + u;
        if (i < total4) {
            f32x4 v = __builtin_nontemporal_load(&((const f32x4*)x)[i]);
            H4 p;
            p.h[0] = (_Float16)v.x; p.h[1] = (_Float16)v.y;
            p.h[2] = (_Float16)v.z; p.h[3] = (_Float16)v.w;
            ((f32x2*)xh)[i] = p.f2;            // reused by layer 0 -> keep cacheable
        }
    }
}

// ---- 2. single-pass PARALLEL scan+seed (decoupled lookback, replaces serial block) ----
// Per 256-node chunk: deg-sum from 8 hist replicas (regs), dinv, block-local scan,
// publish chunk aggregate in ONE atomic word (flag|value -> no fences needed),
// 64-lane ballot lookback (nchunk<=64 resolves in one round), then write int2
// {start,end} ranges + seed replicated cursors from registers.
__global__ __launch_bounds__(256) void scanseed_kernel(
        const int* __restrict__ hist, int* __restrict__ cursor,
        float* __restrict__ dinv, int2* __restrict__ stv,
        int* __restrict__ state, int N) {
    const int b = blockIdx.x, tid = threadIdx.x, lane = tid & 63, wid = tid >> 6;
    __shared__ int ws[4];
    __shared__ int exs;
    int n = b * 256 + tid;
    int h[NREP];
    int d = 0;
    if (n < N) {
#pragma unroll
        for (int r = 0; r < NREP; ++r) { h[r] = hist[(size_t)r * N + n]; d += h[r]; }
        int dc = d < 1 ? 1 : d;
        dinv[n] = rsqrtf((float)dc);
    } else {
#pragma unroll
        for (int r = 0; r < NREP; ++r) h[r] = 0;
    }
    int inc = d;                                   // wave-inclusive scan
#pragma unroll
    for (int off = 1; off < 64; off <<= 1) {
        int t = __shfl_up(inc, off, 64);
        if (lane >= off) inc += t;
    }
    if (lane == 63) ws[wid] = inc;
    __syncthreads();
    if (tid == 0) {                                // inclusive scan of 4 wave totals
        int s = ws[0]; s += ws[1]; ws[1] = s; s += ws[2]; ws[2] = s; s += ws[3]; ws[3] = s;
    }
    __syncthreads();
    const int T   = ws[3];                         // chunk total
    const int lex = (wid ? ws[wid - 1] : 0) + inc - d;   // local exclusive

    if (b == 0) {
        if (tid == 0) {
            __hip_atomic_store(&state[0], (int)(PREFF | (unsigned)T),
                               __ATOMIC_RELAXED, __HIP_MEMORY_SCOPE_AGENT);
            exs = 0;
        }
    } else {
        if (tid == 0)
            __hip_atomic_store(&state[b], (int)(AGGF | (unsigned)T),
                               __ATOMIC_RELAXED, __HIP_MEMORY_SCOPE_AGENT);
        if (wid == 0) {                            // parallel lookback, lane l -> pred b-1-l
            int p = b - 1 - lane;
            for (;;) {
                unsigned w = (lane < b)
                    ? (unsigned)__hip_atomic_load(&state[p], __ATOMIC_RELAXED,
                                                  __HIP_MEMORY_SCOPE_AGENT)
                    : PREFF;                       // out-of-range: prefix-ready, value 0
                unsigned long long pm = __ballot((w & PREFF) != 0);
                int l1 = __ffsll(pm) - 1;          // closest predecessor with full prefix
                unsigned long long am = __ballot((w & (AGGF | PREFF)) != 0);
                unsigned long long need = (1ull << l1) - 1;
                if ((~am & need) == 0) {           // all closer preds have aggregates
                    int contrib = (lane <= l1) ? (int)(w & VMASK) : 0;
#pragma unroll
                    for (int off = 32; off; off >>= 1)
                        contrib += __shfl_xor(contrib, off, 64);
                    if (lane == 0) {
                        __hip_atomic_store(&state[b], (int)(PREFF | (unsigned)(contrib + T)),
                                           __ATOMIC_RELAXED, __HIP_MEMORY_SCOPE_AGENT);
                        exs = contrib;
                    }
                    break;
                }
                __builtin_amdgcn_s_sleep(1);
            }
        }
    }
    __syncthreads();
    int ex = exs;
    if (n < N) {
        int st = ex + lex;
        stv[n] = make_int2(st, st + d);            // aligned 8B range: 1 load in layer waves
        int run = st;
#pragma unroll
        for (int r = 0; r < NREP; ++r) {           // seed replicated cursors from regs
            cursor[(size_t)r * N + n] = run;
            run += h[r];
        }
    }
}

// ---- 3. bucket scatter: packed 4B records, pre-seeded replicated cursors ----
__global__ void bucket_kernel(const int* __restrict__ row, const int* __restrict__ col,
                              const float* __restrict__ dinv,
                              int* __restrict__ cursor, ERec* __restrict__ edges,
                              int E, int N) {
    int rep = blockIdx.x & (NREP - 1);
    int e0 = (blockIdx.x * blockDim.x + threadIdx.x) * EPT;
    int* cur = cursor + (size_t)rep * N;
    int cs[EPT], rs[EPT], pos[EPT];
    float nm[EPT];
#pragma unroll
    for (int u = 0; u < EPT; ++u) {
        int e = e0 + u;
        if (e < E) {
            cs[u] = __builtin_nontemporal_load(&col[e]);
            rs[u] = __builtin_nontemporal_load(&row[e]);
        }
    }
#pragma unroll
    for (int u = 0; u < EPT; ++u) {
        int e = e0 + u;
        if (e < E) {
            nm[u]  = dinv[rs[u]] * dinv[cs[u]];
            pos[u] = atomicAdd(&cur[cs[u]], 1);
        }
    }
#pragma unroll
    for (int u = 0; u < EPT; ++u) {
        int e = e0 + u;
        if (e < E) {
            HS hs; hs.h = (_Float16)nm[u];
            ERec rec = (uint32_t)rs[u] | ((uint32_t)hs.u << 16);
            edges[pos[u]] = rec;               // reused 8x by layers -> cacheable
        }
    }
}

// ---- 4. one layer: predicated two-phase pipelined gather ----
// int2 range load (one 8B dependent load instead of two 4B at chain head)
__global__ __launch_bounds__(256) void layer_kernel(
        const _Float16* __restrict__ cin, _Float16* __restrict__ cout,
        const int2* __restrict__ stv, const ERec* __restrict__ edges, int N) {
    int node = (blockIdx.x * blockDim.x + threadIdx.x) >> 6;
    int lane = threadIdx.x & 63;
    if (node >= N) return;
    int q  = lane >> 4;        // quarter 0..3
    int li = lane & 15;        // lane-in-quarter
    int2 se = stv[node];
    int s = se.x, t = se.y;

    float a[8];
#pragma unroll
    for (int i = 0; i < 8; ++i) a[i] = 0.f;

    for (int base = s; base < t; base += 64) {
        int cnt = t - base; if (cnt > 64) cnt = 64;
        ERec rec = edges[base + (lane < cnt ? lane : cnt - 1)];   // coalesced staging
#pragma unroll
        for (int ph = 0; ph < 2; ++ph) {
            int j0 = ph * 32;
            if (j0 < cnt) {                    // wave-uniform predicate
                uint32_t rr[8];
#pragma unroll
                for (int u = 0; u < 8; ++u) {  // broadcast 8 records first
                    int idx = j0 + 4 * u + q;
                    int ic  = idx < cnt ? idx : cnt - 1;
                    uint32_t r_ = (uint32_t)__shfl((int)rec, ic, 64);
                    if (idx >= cnt) r_ &= 0xffffu;   // zero norm -> fma adds 0
                    rr[u] = r_;
                }
                H8 v[8];
#pragma unroll
                for (int u = 0; u < 8; ++u)    // 8 independent loads, no fma between
                    v[u].f4 = ((const f32x4*)(cin + (size_t)(rr[u] & 0xffffu) * F))[li];
                h2 hacc[4];
#pragma unroll
                for (int c = 0; c < 4; ++c) hacc[c] = (h2)(_Float16)0.f;
#pragma unroll
                for (int u = 0; u < 8; ++u) {
                    HP n; n.u = (rr[u] >> 16) * 0x00010001u;   // dup norm both halves
#pragma unroll
                    for (int c = 0; c < 4; ++c) hacc[c] += n.p * v[u].p[c];  // pk_fma
                }
#pragma unroll
                for (int c = 0; c < 4; ++c) {  // flush to fp32 every 8 edges
                    a[2 * c]     += (float)hacc[c][0];
                    a[2 * c + 1] += (float)hacc[c][1];
                }
            }
        }
    }
    // combine quarters (lanes li, li+16, li+32, li+48 hold same columns)
#pragma unroll
    for (int i = 0; i < 8; ++i) {
        a[i] += __shfl_xor(a[i], 16, 64);
        a[i] += __shfl_xor(a[i], 32, 64);
    }
    if (q == 0) {
        H8 c; c.f4 = ((const f32x4*)(cin + (size_t)node * F))[li];
        H8 o;
#pragma unroll
        for (int i = 0; i < 8; ++i) o.h[i] = (_Float16)((float)c.h[i] - a[i]);
        ((f32x4*)(cout + (size_t)node * F))[li] = o.f4;   // cacheable: next layer gathers it
    }
}

// ---- 5. epilogue: update = sum_l tanh(k_l)*cur_l; h = c*upd+(1-c)*x;
//          out = relu(h @ W^T + b) ----
__global__ __launch_bounds__(256) void final_kernel(
        const float* __restrict__ x, const _Float16* __restrict__ curh,
        const float* __restrict__ W, const float* __restrict__ bias,
        const float* __restrict__ kv, const float* __restrict__ wt,
        float* __restrict__ out, int N, int L) {
    __shared__ float hs[TM * F];
    __shared__ float Wl[KC * 129];
    int tid  = threadIdx.x;
    int row0 = blockIdx.x * TM;
    float cst  = 1.f / (1.f + __expf(-wt[0]));
    float cst1 = 1.f - cst;
    float t[16];
    for (int l = 0; l < L; ++l) t[l] = tanhf(kv[l]);
    const size_t NF = (size_t)N * F;

    for (int j = tid; j < TM * 32; j += 256) {
        int r = j >> 5, qd = j & 31;
        int gr = row0 + r;
        f32x4 hv = {0.f, 0.f, 0.f, 0.f};
        if (gr < N) {
            f32x4 xv = __builtin_nontemporal_load(&((const f32x4*)(x + (size_t)gr * F))[qd]);
            float sx = 0.f, sy = 0.f, sz = 0.f, sw = 0.f;
            for (int l = 0; l < L; ++l) {
                H4 u;
                u.f2 = __builtin_nontemporal_load(
                    &((const f32x2*)(curh + (size_t)l * NF + (size_t)gr * F))[qd]);
                sx += t[l] * (float)u.h[0]; sy += t[l] * (float)u.h[1];
                sz += t[l] * (float)u.h[2]; sw += t[l] * (float)u.h[3];
            }
            hv.x = cst * sx + cst1 * xv.x;
            hv.y = cst * sy + cst1 * xv.y;
            hv.z = cst * sz + cst1 * xv.z;
            hv.w = cst * sw + cst1 * xv.w;
        }
        ((f32x4*)hs)[j] = hv;
    }

    int c  = tid & 127;
    int rg = tid >> 7;
    float acc[16];
#pragma unroll
    for (int i = 0; i < 16; ++i) acc[i] = 0.f;
    for (int kc = 0; kc < F; kc += KC) {
        __syncthreads();
        for (int j = tid; j < KC * F; j += 256) {
            int c2 = j >> 5, kk = j & 31;
            Wl[kk * 129 + c2] = W[(size_t)c2 * F + kc + kk];
        }
        __syncthreads();
#pragma unroll 8
        for (int kk = 0; kk < KC; ++kk) {
            float w = Wl[kk * 129 + c];
#pragma unroll
            for (int r = 0; r < 16; ++r)
                acc[r] += hs[(rg * 16 + r) * F + kc + kk] * w;
        }
    }
    float bv = bias[c];
#pragma unroll
    for (int r = 0; r < 16; ++r) {
        int gr = row0 + rg * 16 + r;
        if (gr < N) {
            float v = acc[r] + bv;
            out[(size_t)gr * F + c] = v > 0.f ? v : 0.f;
        }
    }
}

extern "C" void kernel_launch(void* const* d_in, const int* in_sizes, int n_in,
                              void* d_out, int out_size, void* d_ws, size_t ws_size,
                              hipStream_t stream) {
    const float* x   = (const float*)d_in[0];
    const int*   ei  = (const int*)d_in[1];
    const float* kv  = (const float*)d_in[2];
    const float* wt  = (const float*)d_in[3];
    const float* W   = (const float*)d_in[4];
    const float* b   = (const float*)d_in[5];
    float* out = (float*)d_out;

    const int E = in_sizes[1] / 2;
    const int N = in_sizes[0] / F;      // N <= 16384 (lookback: <=64 chunks)
    const int L = in_sizes[2];
    const int* row = ei;           // edge_index[0]
    const int* col = ei + E;       // edge_index[1]
    const size_t NF = (size_t)N * F;
    const int total4 = (int)(NF / 4);

    size_t off = 0;
    auto alloc = [&](size_t bytes) {
        void* p = (char*)d_ws + off;
        off += (bytes + 255) & ~(size_t)255;
        return p;
    };
    int*      state  = (int*)alloc(256);                    // lookback states (zeroed)
    int*      hist   = (int*)alloc((size_t)NREP * N * 4);   // contiguous after state: 1 memset
    int*      cursor = (int*)alloc((size_t)NREP * N * 4);
    int2*     stv    = (int2*)alloc((size_t)N * 8);
    float*    dinv   = (float*)alloc((size_t)N * 4);
    ERec*     edges  = (ERec*)alloc((size_t)E * sizeof(ERec));
    _Float16* xh     = (_Float16*)alloc(NF * 2);
    _Float16* curh   = (_Float16*)alloc((size_t)L * NF * 2);
    (void)ws_size;

    (void)hipMemsetAsync(state, 0, 256 + (size_t)NREP * N * 4, stream);

    const int work = (E > total4 ? E : total4);
    const int nb_edge = (work + 256 * EPT - 1) / (256 * EPT);   // same geometry for bucket
    convdeg_kernel<<<nb_edge, 256, 0, stream>>>(x, xh, total4, col, hist, E, N);
    scanseed_kernel<<<(N + 255) / 256, 256, 0, stream>>>(hist, cursor, dinv, stv, state, N);
    bucket_kernel<<<nb_edge, 256, 0, stream>>>(row, col, dinv, cursor, edges, E, N);

    for (int l = 0; l < L; ++l) {
        const _Float16* cin = (l == 0) ? xh : curh + (size_t)(l - 1) * NF;
        _Float16* cout = curh + (size_t)l * NF;
        layer_kernel<<<(N * 64 + 255) / 256, 256, 0, stream>>>(cin, cout, stv, edges, N);
    }

    final_kernel<<<(N + TM - 1) / TM, 256, 0, stream>>>(x, curh, W, b, kv, wt, out, N, L);
}

// Round 6
// 204.216 us; speedup vs baseline: 10.4627x; 1.0510x over previous
//
#include <hip/hip_runtime.h>
#include <stdint.h>

#define F 128
#define NREP 8          // cursor/histogram replicas (contention /8)
#define EPT 4           // edges per thread in histogram/bucket (r5-r7 proven)
#define TM 16           // final: 16 rows/block -> 625 blocks (was 32/313, occupancy 12%)
#define KC 32

// decoupled-lookback flag/value packing: E=320000 < 2^25, flags in bits 29/30
#define AGGF  (1u << 29)
#define PREFF (1u << 30)
#define VMASK ((1u << 25) - 1)

typedef float f32x2 __attribute__((ext_vector_type(2)));
typedef float f32x4 __attribute__((ext_vector_type(4)));
typedef _Float16 h2 __attribute__((ext_vector_type(2)));

union H4 { f32x2 f2; _Float16 h[4]; };
union H8 { f32x4 f4; h2 p[4]; _Float16 h[8]; };
union HS { _Float16 h; unsigned short u; };
union HP { uint32_t u; h2 p; };
typedef uint32_t ERec;   // low16 = src node, high16 = fp16 norm

// ---- 1. fused: x(fp32)->xh(fp16) + replicated in-degree histogram ----
__global__ void convdeg_kernel(const float* __restrict__ x, _Float16* __restrict__ xh,
                               int total4, const int* __restrict__ col,
                               int* __restrict__ hist, int E, int N) {
    int rep = blockIdx.x & (NREP - 1);
    int i0 = (blockIdx.x * blockDim.x + threadIdx.x) * EPT;
    int* h = hist + (size_t)rep * N;
#pragma unroll
    for (int u = 0; u < EPT; ++u) {
        int e = i0 + u;
        if (e < E) atomicAdd(&h[__builtin_nontemporal_load(&col[e])], 1);
    }
#pragma unroll
    for (int u = 0; u < EPT; ++u) {
        int i = i0 + u;
        if (i < total4) {
            f32x4 v = __builtin_nontemporal_load(&((const f32x4*)x)[i]);
            H4 p;
            p.h[0] = (_Float16)v.x; p.h[1] = (_Float16)v.y;
            p.h[2] = (_Float16)v.z; p.h[3] = (_Float16)v.w;
            ((f32x2*)xh)[i] = p.f2;            // reused by layer 0 -> keep cacheable
        }
    }
}

// ---- 2. single-pass PARALLEL scan+seed (decoupled lookback, R5-proven) ----
__global__ __launch_bounds__(256) void scanseed_kernel(
        const int* __restrict__ hist, int* __restrict__ cursor,
        float* __restrict__ dinv, int2* __restrict__ stv,
        int* __restrict__ state, int N) {
    const int b = blockIdx.x, tid = threadIdx.x, lane = tid & 63, wid = tid >> 6;
    __shared__ int ws[4];
    __shared__ int exs;
    int n = b * 256 + tid;
    int h[NREP];
    int d = 0;
    if (n < N) {
#pragma unroll
        for (int r = 0; r < NREP; ++r) { h[r] = hist[(size_t)r * N + n]; d += h[r]; }
        int dc = d < 1 ? 1 : d;
        dinv[n] = rsqrtf((float)dc);
    } else {
#pragma unroll
        for (int r = 0; r < NREP; ++r) h[r] = 0;
    }
    int inc = d;                                   // wave-inclusive scan
#pragma unroll
    for (int off = 1; off < 64; off <<= 1) {
        int t = __shfl_up(inc, off, 64);
        if (lane >= off) inc += t;
    }
    if (lane == 63) ws[wid] = inc;
    __syncthreads();
    if (tid == 0) {                                // inclusive scan of 4 wave totals
        int s = ws[0]; s += ws[1]; ws[1] = s; s += ws[2]; ws[2] = s; s += ws[3]; ws[3] = s;
    }
    __syncthreads();
    const int T   = ws[3];                         // chunk total
    const int lex = (wid ? ws[wid - 1] : 0) + inc - d;   // local exclusive

    if (b == 0) {
        if (tid == 0) {
            __hip_atomic_store(&state[0], (int)(PREFF | (unsigned)T),
                               __ATOMIC_RELAXED, __HIP_MEMORY_SCOPE_AGENT);
            exs = 0;
        }
    } else {
        if (tid == 0)
            __hip_atomic_store(&state[b], (int)(AGGF | (unsigned)T),
                               __ATOMIC_RELAXED, __HIP_MEMORY_SCOPE_AGENT);
        if (wid == 0) {                            // parallel lookback, lane l -> pred b-1-l
            int p = b - 1 - lane;
            for (;;) {
                unsigned w = (lane < b)
                    ? (unsigned)__hip_atomic_load(&state[p], __ATOMIC_RELAXED,
                                                  __HIP_MEMORY_SCOPE_AGENT)
                    : PREFF;                       // out-of-range: prefix-ready, value 0
                unsigned long long pm = __ballot((w & PREFF) != 0);
                int l1 = __ffsll(pm) - 1;          // closest predecessor with full prefix
                unsigned long long am = __ballot((w & (AGGF | PREFF)) != 0);
                unsigned long long need = (1ull << l1) - 1;
                if ((~am & need) == 0) {           // all closer preds have aggregates
                    int contrib = (lane <= l1) ? (int)(w & VMASK) : 0;
#pragma unroll
                    for (int off = 32; off; off >>= 1)
                        contrib += __shfl_xor(contrib, off, 64);
                    if (lane == 0) {
                        __hip_atomic_store(&state[b], (int)(PREFF | (unsigned)(contrib + T)),
                                           __ATOMIC_RELAXED, __HIP_MEMORY_SCOPE_AGENT);
                        exs = contrib;
                    }
                    break;
                }
                __builtin_amdgcn_s_sleep(1);
            }
        }
    }
    __syncthreads();
    int ex = exs;
    if (n < N) {
        int st = ex + lex;
        stv[n] = make_int2(st, st + d);            // aligned 8B range: 1 load in layer waves
        int run = st;
#pragma unroll
        for (int r = 0; r < NREP; ++r) {           // seed replicated cursors from regs
            cursor[(size_t)r * N + n] = run;
            run += h[r];
        }
    }
}

// ---- 3. bucket scatter: packed 4B records, pre-seeded replicated cursors ----
__global__ void bucket_kernel(const int* __restrict__ row, const int* __restrict__ col,
                              const float* __restrict__ dinv,
                              int* __restrict__ cursor, ERec* __restrict__ edges,
                              int E, int N) {
    int rep = blockIdx.x & (NREP - 1);
    int e0 = (blockIdx.x * blockDim.x + threadIdx.x) * EPT;
    int* cur = cursor + (size_t)rep * N;
    int cs[EPT], rs[EPT], pos[EPT];
    float nm[EPT];
#pragma unroll
    for (int u = 0; u < EPT; ++u) {
        int e = e0 + u;
        if (e < E) {
            cs[u] = __builtin_nontemporal_load(&col[e]);
            rs[u] = __builtin_nontemporal_load(&row[e]);
        }
    }
#pragma unroll
    for (int u = 0; u < EPT; ++u) {
        int e = e0 + u;
        if (e < E) {
            nm[u]  = dinv[rs[u]] * dinv[cs[u]];
            pos[u] = atomicAdd(&cur[cs[u]], 1);
        }
    }
#pragma unroll
    for (int u = 0; u < EPT; ++u) {
        int e = e0 + u;
        if (e < E) {
            HS hs; hs.h = (_Float16)nm[u];
            ERec rec = (uint32_t)rs[u] | ((uint32_t)hs.u << 16);
            edges[pos[u]] = rec;               // reused 8x by layers -> cacheable
        }
    }
}

// ---- 4. one layer: predicated two-phase pipelined gather (unchanged, R5) ----
__global__ __launch_bounds__(256) void layer_kernel(
        const _Float16* __restrict__ cin, _Float16* __restrict__ cout,
        const int2* __restrict__ stv, const ERec* __restrict__ edges, int N) {
    int node = (blockIdx.x * blockDim.x + threadIdx.x) >> 6;
    int lane = threadIdx.x & 63;
    if (node >= N) return;
    int q  = lane >> 4;        // quarter 0..3
    int li = lane & 15;        // lane-in-quarter
    int2 se = stv[node];
    int s = se.x, t = se.y;

    float a[8];
#pragma unroll
    for (int i = 0; i < 8; ++i) a[i] = 0.f;

    for (int base = s; base < t; base += 64) {
        int cnt = t - base; if (cnt > 64) cnt = 64;
        ERec rec = edges[base + (lane < cnt ? lane : cnt - 1)];   // coalesced staging
#pragma unroll
        for (int ph = 0; ph < 2; ++ph) {
            int j0 = ph * 32;
            if (j0 < cnt) {                    // wave-uniform predicate
                uint32_t rr[8];
#pragma unroll
                for (int u = 0; u < 8; ++u) {  // broadcast 8 records first
                    int idx = j0 + 4 * u + q;
                    int ic  = idx < cnt ? idx : cnt - 1;
                    uint32_t r_ = (uint32_t)__shfl((int)rec, ic, 64);
                    if (idx >= cnt) r_ &= 0xffffu;   // zero norm -> fma adds 0
                    rr[u] = r_;
                }
                H8 v[8];
#pragma unroll
                for (int u = 0; u < 8; ++u)    // 8 independent loads, no fma between
                    v[u].f4 = ((const f32x4*)(cin + (size_t)(rr[u] & 0xffffu) * F))[li];
                h2 hacc[4];
#pragma unroll
                for (int c = 0; c < 4; ++c) hacc[c] = (h2)(_Float16)0.f;
#pragma unroll
                for (int u = 0; u < 8; ++u) {
                    HP n; n.u = (rr[u] >> 16) * 0x00010001u;   // dup norm both halves
#pragma unroll
                    for (int c = 0; c < 4; ++c) hacc[c] += n.p * v[u].p[c];  // pk_fma
                }
#pragma unroll
                for (int c = 0; c < 4; ++c) {  // flush to fp32 every 8 edges
                    a[2 * c]     += (float)hacc[c][0];
                    a[2 * c + 1] += (float)hacc[c][1];
                }
            }
        }
    }
    // combine quarters (lanes li, li+16, li+32, li+48 hold same columns)
#pragma unroll
    for (int i = 0; i < 8; ++i) {
        a[i] += __shfl_xor(a[i], 16, 64);
        a[i] += __shfl_xor(a[i], 32, 64);
    }
    if (q == 0) {
        H8 c; c.f4 = ((const f32x4*)(cin + (size_t)node * F))[li];
        H8 o;
#pragma unroll
        for (int i = 0; i < 8; ++i) o.h[i] = (_Float16)((float)c.h[i] - a[i]);
        ((f32x4*)(cout + (size_t)node * F))[li] = o.f4;   // cacheable: next layer gathers it
    }
}

// ---- 5. epilogue v2: TM=16 (625 blocks), register tv[] (no scratch),
//         one (row, 8-col-oct) per thread in h phase (8 independent 16B loads) ----
__global__ __launch_bounds__(256) void final_kernel(
        const float* __restrict__ x, const _Float16* __restrict__ curh,
        const float* __restrict__ W, const float* __restrict__ bias,
        const float* __restrict__ kv, const float* __restrict__ wt,
        float* __restrict__ out, int N, int L) {
    __shared__ float hs[TM * F];       // 8 KB
    __shared__ float Wl[KC * 129];     // 16.5 KB
    int tid  = threadIdx.x;
    int row0 = blockIdx.x * TM;
    float cst  = 1.f / (1.f + __expf(-wt[0]));
    float cst1 = 1.f - cst;
    // static-indexed (registers, NOT scratch): unroll to compile-time bound, predicate on L
    float tv[16];
#pragma unroll
    for (int l = 0; l < 16; ++l) tv[l] = (l < 16 && l < L) ? tanhf(kv[l]) : 0.f;
    const size_t NF = (size_t)N * F;

    {   // h phase: thread tid owns row r = tid>>4, oct oc = tid&15 (8 columns); one shot
        int r  = tid >> 4;
        int oc = tid & 15;
        int gr = row0 + r;
        f32x4 h0 = {0.f, 0.f, 0.f, 0.f}, h1 = {0.f, 0.f, 0.f, 0.f};
        if (gr < N) {
            const f32x4* xr = (const f32x4*)(x + (size_t)gr * F) + oc * 2;
            f32x4 x0 = __builtin_nontemporal_load(xr);
            f32x4 x1 = __builtin_nontemporal_load(xr + 1);
            float s[8];
#pragma unroll
            for (int i = 0; i < 8; ++i) s[i] = 0.f;
#pragma unroll
            for (int l = 0; l < 16; ++l) {
                if (l < L) {                      // uniform predicate; loads stay independent
                    H8 u;
                    u.f4 = __builtin_nontemporal_load(
                        (const f32x4*)(curh + (size_t)l * NF + (size_t)gr * F) + oc);
#pragma unroll
                    for (int i = 0; i < 8; ++i) s[i] += tv[l] * (float)u.h[i];
                }
            }
#pragma unroll
            for (int i = 0; i < 4; ++i) {
                h0[i] = cst * s[i]     + cst1 * x0[i];
                h1[i] = cst * s[4 + i] + cst1 * x1[i];
            }
        }
        ((f32x4*)hs)[tid * 2]     = h0;           // hs[r*F + oc*8 ..] == (f32x4*)hs[tid*2]
        ((f32x4*)hs)[tid * 2 + 1] = h1;
    }

    int c  = tid & 127;
    int rg = tid >> 7;                            // 2 row-groups of 8
    float acc[8];
#pragma unroll
    for (int i = 0; i < 8; ++i) acc[i] = 0.f;
    for (int kc = 0; kc < F; kc += KC) {
        __syncthreads();                          // first iter also covers hs writes
        for (int j = tid; j < KC * F; j += 256) {
            int c2 = j >> 5, kk = j & 31;
            Wl[kk * 129 + c2] = W[(size_t)c2 * F + kc + kk];
        }
        __syncthreads();
#pragma unroll 8
        for (int kk = 0; kk < KC; ++kk) {
            float w = Wl[kk * 129 + c];
#pragma unroll
            for (int r = 0; r < 8; ++r)
                acc[r] += hs[(rg * 8 + r) * F + kc + kk] * w;
        }
    }
    float bv = bias[c];
#pragma unroll
    for (int r = 0; r < 8; ++r) {
        int gr = row0 + rg * 8 + r;
        if (gr < N) {
            float v = acc[r] + bv;
            out[(size_t)gr * F + c] = v > 0.f ? v : 0.f;
        }
    }
}

extern "C" void kernel_launch(void* const* d_in, const int* in_sizes, int n_in,
                              void* d_out, int out_size, void* d_ws, size_t ws_size,
                              hipStream_t stream) {
    const float* x   = (const float*)d_in[0];
    const int*   ei  = (const int*)d_in[1];
    const float* kv  = (const float*)d_in[2];
    const float* wt  = (const float*)d_in[3];
    const float* W   = (const float*)d_in[4];
    const float* b   = (const float*)d_in[5];
    float* out = (float*)d_out;

    const int E = in_sizes[1] / 2;
    const int N = in_sizes[0] / F;      // N <= 16384 (lookback: <=64 chunks)
    const int L = in_sizes[2];
    const int* row = ei;           // edge_index[0]
    const int* col = ei + E;       // edge_index[1]
    const size_t NF = (size_t)N * F;
    const int total4 = (int)(NF / 4);

    size_t off = 0;
    auto alloc = [&](size_t bytes) {
        void* p = (char*)d_ws + off;
        off += (bytes + 255) & ~(size_t)255;
        return p;
    };
    int*      state  = (int*)alloc(256);                    // lookback states (zeroed)
    int*      hist   = (int*)alloc((size_t)NREP * N * 4);   // contiguous after state: 1 memset
    int*      cursor = (int*)alloc((size_t)NREP * N * 4);
    int2*     stv    = (int2*)alloc((size_t)N * 8);
    float*    dinv   = (float*)alloc((size_t)N * 4);
    ERec*     edges  = (ERec*)alloc((size_t)E * sizeof(ERec));
    _Float16* xh     = (_Float16*)alloc(NF * 2);
    _Float16* curh   = (_Float16*)alloc((size_t)L * NF * 2);
    (void)ws_size;

    (void)hipMemsetAsync(state, 0, 256 + (size_t)NREP * N * 4, stream);

    const int work = (E > total4 ? E : total4);
    const int nb_edge = (work + 256 * EPT - 1) / (256 * EPT);   // same geometry for bucket
    convdeg_kernel<<<nb_edge, 256, 0, stream>>>(x, xh, total4, col, hist, E, N);
    scanseed_kernel<<<(N + 255) / 256, 256, 0, stream>>>(hist, cursor, dinv, stv, state, N);
    bucket_kernel<<<nb_edge, 256, 0, stream>>>(row, col, dinv, cursor, edges, E, N);

    for (int l = 0; l < L; ++l) {
        const _Float16* cin = (l == 0) ? xh : curh + (size_t)(l - 1) * NF;
        _Float16* cout = curh + (size_t)l * NF;
        layer_kernel<<<(N * 64 + 255) / 256, 256, 0, stream>>>(cin, cout, stv, edges, N);
    }

    final_kernel<<<(N + TM - 1) / TM, 256, 0, stream>>>(x, curh, W, b, kv, wt, out, N, L);
}